// Round 8
// baseline (1035.869 us; speedup 1.0000x reference)
//
#include <hip/hip_runtime.h>
#include <hip/hip_bf16.h>

typedef unsigned short u16;
typedef unsigned int u32;
typedef __attribute__((ext_vector_type(8))) short bf16x8;
typedef __attribute__((ext_vector_type(4))) float f32x4;
typedef __attribute__((ext_vector_type(4))) float float4v;

__device__ __forceinline__ float bf2f(u16 v) {
  union { u32 u; float f; } x; x.u = ((u32)v) << 16; return x.f;
}
__device__ __forceinline__ u16 f2bf(float f) {
  union { u32 u; float f; } x; x.f = f;
  return (u16)((x.u + 0x7fffu + ((x.u >> 16) & 1u)) >> 16);
}

__device__ __forceinline__ void gload16(const void* g, void* l) {
  __builtin_amdgcn_global_load_lds(
      (const __attribute__((address_space(1))) u32*)g,
      (__attribute__((address_space(3))) u32*)l, 16, 0, 0);
}

#define MFMA16(a, bfr, cacc) __builtin_amdgcn_mfma_f32_16x16x32_bf16((a), (bfr), (cacc), 0, 0, 0)

// ---------------- prep kernels ----------------

__global__ void transpose_kernel(const float* __restrict__ in, u16* __restrict__ out,
                                 int R, int C) {
  int t = blockIdx.x * blockDim.x + threadIdx.x;
  if (t >= R * C) return;
  int c = t / R, r = t % R;
  out[t] = f2bf(in[r * C + c]);
}

// w_qkv -> per-(tensor,head) fragment-contiguous layout:
// bw2[whead*16384 + ((kk*2+dt)*4+lg)*128 + li*8 + e]
//   = bf16(w_qkv[(kk*32+lg*8+e)*1536 + s*512 + h*32 + dt*16 + li]), whead = s*16+h
__global__ void wqkv_swz_kernel(const float* __restrict__ w, u16* __restrict__ out) {
  int t = blockIdx.x * blockDim.x + threadIdx.x;
  if (t >= 48 * 16384) return;
  int whead = t >> 14;
  int rest = t & 16383;
  int chunk = rest >> 7;          // 0..127
  int kk = chunk >> 3, dt = (chunk >> 2) & 1, lg = chunk & 3;
  int li = (rest >> 3) & 15, e = rest & 7;
  int s = whead >> 4, h = whead & 15;
  out[t] = f2bf(w[(size_t)(kk * 32 + lg * 8 + e) * 1536 + s * 512 + h * 32 + dt * 16 + li]);
}

__global__ void bias_tab_kernel(const float* __restrict__ w1, const float* __restrict__ w2,
                                float* __restrict__ tab) {
  int t = blockIdx.x * blockDim.x + threadIdx.x;
  if (t >= 225 * 16) return;
  int r = t >> 4, h = t & 15;
  int i = r / 15, j = r % 15;
  float gi = (float)(i - 7) * (8.0f / 7.0f);
  float gj = (float)(j - 7) * (8.0f / 7.0f);
  float si = (gi > 0.f) ? 1.f : ((gi < 0.f) ? -1.f : 0.f);
  float sj = (gj > 0.f) ? 1.f : ((gj < 0.f) ? -1.f : 0.f);
  float t0 = si * log2f(fabsf(gi) + 1.0f) * (1.0f / 3.0f);
  float t1 = sj * log2f(fabsf(gj) + 1.0f) * (1.0f / 3.0f);
  float acc = 0.f;
  for (int k = 0; k < 512; ++k) {
    float a = t0 * w1[k] + t1 * w1[512 + k];
    float hs = a * fminf(fmaxf(a + 3.f, 0.f), 6.f) * (1.f / 6.f);
    acc += hs * w2[k * 16 + h];
  }
  tab[t] = acc;
}

__global__ void bias16_kernel(const float* __restrict__ tab, float* __restrict__ b16) {
  int t = blockIdx.x * blockDim.x + threadIdx.x;
  if (t >= 16 * 64 * 64) return;
  int h = t >> 12, nm = t & 4095, n = nm >> 6, m = nm & 63;
  int idx = ((n >> 3) - (m >> 3) + 7) * 15 + ((n & 7) - (m & 7) + 7);
  float b = tab[idx * 16 + h];
  b16[t] = 16.0f / (1.0f + expf(-b));
}

// ---------------- m97-style bf16 GEMM: C[M,N] = A[M,K] * Bt[N,K]^T ----------------
template <bool F32OUT>
__global__ __launch_bounds__(256) void gemm_bt(const u16* __restrict__ A,
                                               const u16* __restrict__ Bt,
                                               void* __restrict__ Cout,
                                               int M, int N, int K) {
  __shared__ u16 lA[128 * 64];
  __shared__ u16 lB[128 * 64];
  const int tid = threadIdx.x;
  const int w = tid >> 6, l = tid & 63;
  const int lg = l >> 4, li = l & 15;
  const int nbn = N >> 7;
  const int nwg = gridDim.x;
  int bidx = blockIdx.x;
  int q = nwg >> 3, r = nwg & 7;
  int xcd = bidx & 7, pos = bidx >> 3;
  int swz = (xcd < r ? xcd * (q + 1) : r * (q + 1) + (xcd - r) * q) + pos;
  int bm = swz / nbn, bn = swz % nbn;
  const int wr = w >> 1, wc = w & 1;

  f32x4 acc[4][4];
#pragma unroll
  for (int i = 0; i < 4; i++)
#pragma unroll
    for (int j = 0; j < 4; j++) acc[i][j] = (f32x4){0.f, 0.f, 0.f, 0.f};

  const u16* Abase = A + (size_t)(bm * 128) * K;
  const u16* Bbase = Bt + (size_t)(bn * 128) * K;

  for (int k0 = 0; k0 < K; k0 += 64) {
#pragma unroll
    for (int i = 0; i < 4; ++i) {
      int c = w * 256 + i * 64 + l;
      int row = c >> 3, kc = c & 7;
      gload16(Abase + (size_t)row * K + k0 + kc * 8, (u16*)lA + c * 8);
      gload16(Bbase + (size_t)row * K + k0 + kc * 8, (u16*)lB + c * 8);
    }
    __syncthreads();
#pragma unroll
    for (int kk = 0; kk < 2; ++kk) {
      bf16x8 af[4], bfr[4];
#pragma unroll
      for (int t = 0; t < 4; ++t) {
        int row = wr * 64 + t * 16 + li;
        af[t] = *(const bf16x8*)&lA[row * 64 + kk * 32 + lg * 8];
        int col = wc * 64 + t * 16 + li;
        bfr[t] = *(const bf16x8*)&lB[col * 64 + kk * 32 + lg * 8];
      }
#pragma unroll
      for (int tm = 0; tm < 4; ++tm)
#pragma unroll
        for (int tn = 0; tn < 4; ++tn)
          acc[tm][tn] = MFMA16(af[tm], bfr[tn], acc[tm][tn]);
    }
    __syncthreads();
  }
  int r0 = bm * 128 + wr * 64 + lg * 4;
  int c0 = bn * 128 + wc * 64 + li;
#pragma unroll
  for (int tm = 0; tm < 4; ++tm)
#pragma unroll
    for (int tn = 0; tn < 4; ++tn)
#pragma unroll
      for (int j = 0; j < 4; ++j) {
        size_t off = (size_t)(r0 + tm * 16 + j) * N + c0 + tn * 16;
        if (F32OUT)
          ((float*)Cout)[off] = acc[tm][tn][j];
        else
          ((u16*)Cout)[off] = f2bf(acc[tm][tn][j]);
      }
}

// ---------------- fused: x->qkv GEMM -> cosine attn -> head-softmax -> PV ----------
// 1 block = 1 window, 8 waves x 512 threads; each wave owns heads (w, w+8).
// 512 threads = 2 waves/SIMD -> 256 VGPR/lane budget; all phases fit (<=~225).
__global__ __launch_bounds__(512, 2) void fused_attn(
    const float* __restrict__ x, const float* __restrict__ mask,
    const u16* __restrict__ wqkv2, const float* __restrict__ bias16,
    const float* __restrict__ lscale, u16* __restrict__ aout) {
  __shared__ float S[33280];  // 133,120 B region, reused across phases
  u16* xl = (u16*)S;          // [64 rows][64 chunks16B] bf16, XOR-swizzled (64 KB)
  u16* bb = xl + 32768;       // q/k bounce: [16h][64n][32d] bf16, swizzled (64 KB)
  float* ob = S;              // phase 4: [64][516] f32
  u16* P16 = (u16*)S;         // phase 3: bf16 P in-place (low half of f32 slots)

  const int tid = threadIdx.x;
  const int w = tid >> 6, l = tid & 63;
  const int lg = l >> 4, li = l & 15;
  const int b = blockIdx.x, wm = b & 63;
  const float* xg = x + (size_t)b * 64 * 512;

  // ---- phase 0: stage x fp32 -> bf16 LDS (16B-chunk index XOR n&7) ----
  {
    int n = tid >> 3, seg = tid & 7;
    const float4v* src = (const float4v*)(xg + n * 512 + seg * 64);
#pragma unroll
    for (int i = 0; i < 8; ++i) {
      float4v a = src[2 * i], c = src[2 * i + 1];
      union { bf16x8 v; u16 s[8]; } o;
      o.s[0] = f2bf(a[0]); o.s[1] = f2bf(a[1]); o.s[2] = f2bf(a[2]); o.s[3] = f2bf(a[3]);
      o.s[4] = f2bf(c[0]); o.s[5] = f2bf(c[1]); o.s[6] = f2bf(c[2]); o.s[7] = f2bf(c[3]);
      *(bf16x8*)(xl + ((n * 64 + ((seg * 8 + i) ^ (n & 7))) << 3)) = o.v;
    }
  }
  float sc[2];
#pragma unroll
  for (int hp = 0; hp < 2; ++hp)
    sc[hp] = __expf(fminf(lscale[w + hp * 8], 4.6051702f));
  __syncthreads();

  bf16x8 qf[2][4], kf[2][4];

  // ---- phase 1: q,k GEMM for BOTH heads; in-place norm fold; bounce to frags ----
  {
    f32x4 qa[2][4][2], ka[2][4][2];
#pragma unroll
    for (int hp = 0; hp < 2; ++hp)
#pragma unroll
      for (int rt = 0; rt < 4; ++rt)
#pragma unroll
        for (int dt = 0; dt < 2; ++dt) {
          qa[hp][rt][dt] = (f32x4){0.f, 0.f, 0.f, 0.f};
          ka[hp][rt][dt] = (f32x4){0.f, 0.f, 0.f, 0.f};
        }
#pragma unroll
    for (int kk = 0; kk < 16; ++kk) {
      bf16x8 ax[4];
#pragma unroll
      for (int rt = 0; rt < 4; ++rt) {
        int n = rt * 16 + li;
        ax[rt] = *(const bf16x8*)(xl + ((n * 64 + ((kk * 4 + lg) ^ (n & 7))) << 3));
      }
#pragma unroll
      for (int dt = 0; dt < 2; ++dt) {
        int coff = (kk * 2 + dt) * 512 + lg * 128 + li * 8;
#pragma unroll
        for (int hp = 0; hp < 2; ++hp) {
          int h = w + hp * 8;
          bf16x8 fq = *(const bf16x8*)(wqkv2 + (size_t)h * 16384 + coff);
          bf16x8 fk = *(const bf16x8*)(wqkv2 + (size_t)(16 + h) * 16384 + coff);
#pragma unroll
          for (int rt = 0; rt < 4; ++rt) {
            qa[hp][rt][dt] = MFMA16(ax[rt], fq, qa[hp][rt][dt]);
            ka[hp][rt][dt] = MFMA16(ax[rt], fk, ka[hp][rt][dt]);
          }
        }
      }
    }
    // norms: reduce over d (li lanes), scale accs in place
#pragma unroll
    for (int hp = 0; hp < 2; ++hp)
#pragma unroll
      for (int rt = 0; rt < 4; ++rt) {
        f32x4 q2, k2;
#pragma unroll
        for (int j = 0; j < 4; ++j) {
          q2[j] = qa[hp][rt][0][j] * qa[hp][rt][0][j] + qa[hp][rt][1][j] * qa[hp][rt][1][j];
          k2[j] = ka[hp][rt][0][j] * ka[hp][rt][0][j] + ka[hp][rt][1][j] * ka[hp][rt][1][j];
        }
#pragma unroll
        for (int s = 1; s <= 8; s <<= 1)
#pragma unroll
          for (int j = 0; j < 4; ++j) {
            q2[j] += __shfl_xor(q2[j], s);
            k2[j] += __shfl_xor(k2[j], s);
          }
#pragma unroll
        for (int j = 0; j < 4; ++j) {
          float rq = sc[hp] / fmaxf(sqrtf(q2[j]), 1e-12f);
          float rk = 1.0f / fmaxf(sqrtf(k2[j]), 1e-12f);
#pragma unroll
          for (int dt = 0; dt < 2; ++dt) {
            qa[hp][rt][dt][j] *= rq;
            ka[hp][rt][dt][j] *= rk;
          }
        }
      }
    // bounce q (both heads) -> read qf -> bounce k -> read kf (3 barriers)
#pragma unroll
    for (int hp = 0; hp < 2; ++hp) {
      int h = w + hp * 8;
#pragma unroll
      for (int rt = 0; rt < 4; ++rt)
#pragma unroll
        for (int dt = 0; dt < 2; ++dt)
#pragma unroll
          for (int j = 0; j < 4; ++j) {
            int n = rt * 16 + lg * 4 + j;
            int d = dt * 16 + li;
            int s = (n ^ (n >> 2)) & 3;
            bb[h * 2048 + n * 32 + (((d >> 3) ^ s) << 3) + (d & 7)] = f2bf(qa[hp][rt][dt][j]);
          }
    }
    __syncthreads();
#pragma unroll
    for (int hp = 0; hp < 2; ++hp) {
      int h = w + hp * 8;
#pragma unroll
      for (int t = 0; t < 4; ++t) {
        int n = t * 16 + li;
        int s = (n ^ (n >> 2)) & 3;
        qf[hp][t] = *(const bf16x8*)(bb + h * 2048 + n * 32 + ((lg ^ s) << 3));
      }
    }
    __syncthreads();
#pragma unroll
    for (int hp = 0; hp < 2; ++hp) {
      int h = w + hp * 8;
#pragma unroll
      for (int rt = 0; rt < 4; ++rt)
#pragma unroll
        for (int dt = 0; dt < 2; ++dt)
#pragma unroll
          for (int j = 0; j < 4; ++j) {
            int n = rt * 16 + lg * 4 + j;
            int d = dt * 16 + li;
            int s = (n ^ (n >> 2)) & 3;
            bb[h * 2048 + n * 32 + (((d >> 3) ^ s) << 3) + (d & 7)] = f2bf(ka[hp][rt][dt][j]);
          }
    }
    __syncthreads();
#pragma unroll
    for (int hp = 0; hp < 2; ++hp) {
      int h = w + hp * 8;
#pragma unroll
      for (int t = 0; t < 4; ++t) {
        int n = t * 16 + li;
        int s = (n ^ (n >> 2)) & 3;
        kf[hp][t] = *(const bf16x8*)(bb + h * 2048 + n * 32 + ((lg ^ s) << 3));
      }
    }
  }

  // ---- phase 2: V GEMM for both heads (x still in LDS); va stays in regs ----
  f32x4 va[2][4][2];
#pragma unroll
  for (int hp = 0; hp < 2; ++hp)
#pragma unroll
    for (int rt = 0; rt < 4; ++rt)
#pragma unroll
      for (int dt = 0; dt < 2; ++dt) va[hp][rt][dt] = (f32x4){0.f, 0.f, 0.f, 0.f};
  {
#pragma unroll
    for (int kk = 0; kk < 16; ++kk) {
      bf16x8 ax[4];
#pragma unroll
      for (int rt = 0; rt < 4; ++rt) {
        int n = rt * 16 + li;
        ax[rt] = *(const bf16x8*)(xl + ((n * 64 + ((kk * 4 + lg) ^ (n & 7))) << 3));
      }
#pragma unroll
      for (int dt = 0; dt < 2; ++dt) {
        int coff = (kk * 2 + dt) * 512 + lg * 128 + li * 8;
#pragma unroll
        for (int hp = 0; hp < 2; ++hp) {
          int h = w + hp * 8;
          bf16x8 fv = *(const bf16x8*)(wqkv2 + (size_t)(32 + h) * 16384 + coff);
#pragma unroll
          for (int rt = 0; rt < 4; ++rt) va[hp][rt][dt] = MFMA16(ax[rt], fv, va[hp][rt][dt]);
        }
      }
    }
  }
  __syncthreads();  // x + bounce dead; S region live next

  const float* mask_w = mask + wm * 4096;
  f32x4 oacc[2][4][2];
#pragma unroll
  for (int hp = 0; hp < 2; ++hp)
#pragma unroll
    for (int i = 0; i < 4; i++) {
      oacc[hp][i][0] = (f32x4){0.f, 0.f, 0.f, 0.f};
      oacc[hp][i][1] = (f32x4){0.f, 0.f, 0.f, 0.f};
    }

  // ---- phase 3: two 32-key chunks: QK^T -> +bias+mask -> head-softmax -> PV ----
#pragma unroll
  for (int c = 0; c < 2; ++c) {
#pragma unroll
    for (int hp = 0; hp < 2; ++hp) {
      int h = w + hp * 8;
      const float* bias_h = bias16 + h * 4096;
#pragma unroll
      for (int tn = 0; tn < 4; ++tn)
#pragma unroll
        for (int t = 0; t < 2; ++t) {
          int mt = c * 2 + t;
          f32x4 z = {0.f, 0.f, 0.f, 0.f};
          f32x4 s = MFMA16(qf[hp][tn], kf[hp][mt], z);
          int mloc = t * 16 + li;
          int mg = c * 32 + mloc;
#pragma unroll
          for (int j = 0; j < 4; ++j) {
            int n = tn * 16 + lg * 4 + j;
            S[h * 2080 + mloc * 65 + n] = s[j] + bias_h[n * 64 + mg] + mask_w[n * 64 + mg];
          }
        }
    }
    __syncthreads();
    // softmax over 16 heads per (m,n): 2048 pairs / 512 threads = 4 each
#pragma unroll
    for (int pp = 0; pp < 4; ++pp) {
      int p = tid + pp * 512;
      int base = (p >> 6) * 65 + (p & 63);
      float mx = -3.0e38f;
#pragma unroll
      for (int hh = 0; hh < 16; ++hh) mx = fmaxf(mx, S[hh * 2080 + base]);
      float sum = 0.f;
#pragma unroll
      for (int hh = 0; hh < 16; ++hh) {
        float e = __expf(S[hh * 2080 + base] - mx);
        S[hh * 2080 + base] = e;
        sum += e;
      }
      float inv = 1.0f / sum;
#pragma unroll
      for (int hh = 0; hh < 16; ++hh)
        P16[(hh * 2080 + base) * 2] = f2bf(S[hh * 2080 + base] * inv);
    }
    __syncthreads();
    // PV for both heads: V frags via shuffles, P frags as bf16 from LDS
#pragma unroll
    for (int hp = 0; hp < 2; ++hp) {
      int h = w + hp * 8;
      bf16x8 vf[2];
#pragma unroll
      for (int td = 0; td < 2; ++td)
#pragma unroll
        for (int j = 0; j < 8; ++j) {
          int srcl = (((lg * 2 + (j >> 2)) & 3) << 4) + li;
          float a0 = __shfl(va[hp][c * 2][td][j & 3], srcl);
          float a1 = __shfl(va[hp][c * 2 + 1][td][j & 3], srcl);
          vf[td][j] = (short)f2bf(lg >= 2 ? a1 : a0);
        }
#pragma unroll
      for (int tn = 0; tn < 4; ++tn) {
        bf16x8 pf;
#pragma unroll
        for (int e = 0; e < 8; ++e)
          pf[e] = (short)P16[(h * 2080 + (lg * 8 + e) * 65 + tn * 16 + li) * 2];
        oacc[hp][tn][0] = MFMA16(pf, vf[0], oacc[hp][tn][0]);
        oacc[hp][tn][1] = MFMA16(pf, vf[1], oacc[hp][tn][1]);
      }
    }
    __syncthreads();  // S reused by next chunk (or ob)
  }

  // ---- phase 4: coalesced output via LDS bounce ----
#pragma unroll
  for (int hp = 0; hp < 2; ++hp) {
    int h = w + hp * 8;
#pragma unroll
    for (int tn = 0; tn < 4; ++tn)
#pragma unroll
      for (int td = 0; td < 2; ++td)
#pragma unroll
        for (int j = 0; j < 4; ++j) {
          int n = tn * 16 + lg * 4 + j;
          ob[n * 516 + h * 32 + td * 16 + li] = oacc[hp][tn][td][j];
        }
  }
  __syncthreads();
  {
    int n = tid >> 3, seg = tid & 7;
    u16* dst = aout + ((size_t)b * 64 + n) * 512 + seg * 64;
    const float* srcr = ob + n * 516 + seg * 64;
#pragma unroll
    for (int i = 0; i < 8; ++i) {
      union { bf16x8 v; u16 s[8]; } o;
#pragma unroll
      for (int e = 0; e < 8; ++e) o.s[e] = f2bf(srcr[i * 8 + e]);
      *(bf16x8*)(dst + i * 8) = o.v;
    }
  }
}

extern "C" void kernel_launch(void* const* d_in, const int* in_sizes, int n_in,
                              void* d_out, int out_size, void* d_ws, size_t ws_size,
                              hipStream_t stream) {
  const float* x = (const float*)d_in[0];
  const float* mask = (const float*)d_in[1];
  const float* w_qkv = (const float*)d_in[2];
  const float* w_out = (const float*)d_in[3];
  const float* cpb_w1 = (const float*)d_in[4];
  const float* cpb_w2 = (const float*)d_in[5];
  const float* lscale = (const float*)d_in[6];
  float* out = (float*)d_out;

  char* ws = (char*)d_ws;
  u16* wqkv2 = (u16*)ws;                    // 1,572,864 B (swizzled frag layout)
  u16* woutT = (u16*)(ws + 1572864ull);     // 524,288 B
  float* btab = (float*)(ws + 2097152ull);  // 16,384 B
  float* b16 = (float*)(ws + 2113536ull);   // 262,144 B
  u16* attn_out = (u16*)(ws + 2375680ull);  // 134,217,728 B

  wqkv_swz_kernel<<<(48 * 16384) / 256, 256, 0, stream>>>(w_qkv, wqkv2);
  transpose_kernel<<<(512 * 512 + 255) / 256, 256, 0, stream>>>(w_out, woutT, 512, 512);
  bias_tab_kernel<<<(225 * 16 + 255) / 256, 256, 0, stream>>>(cpb_w1, cpb_w2, btab);
  bias16_kernel<<<(16 * 64 * 64 + 255) / 256, 256, 0, stream>>>(btab, b16);

  // fused x->qkv->attention, one block per window (512 threads, 2 heads/wave)
  fused_attn<<<2048, 512, 0, stream>>>(x, mask, wqkv2, b16, lscale, attn_out);

  // out = attn_out @ w_out  (M=131072, N=512, K=512), fp32 stores
  gemm_bt<true><<<4096, 256, 0, stream>>>(attn_out, woutT, out, 131072, 512, 512);
}

// Round 9
// 991.048 us; speedup vs baseline: 1.0452x; 1.0452x over previous
//
#include <hip/hip_runtime.h>
#include <hip/hip_bf16.h>

typedef unsigned short u16;
typedef unsigned int u32;
typedef __attribute__((ext_vector_type(8))) short bf16x8;
typedef __attribute__((ext_vector_type(4))) float f32x4;
typedef __attribute__((ext_vector_type(4))) float float4v;

__device__ __forceinline__ float bf2f(u16 v) {
  union { u32 u; float f; } x; x.u = ((u32)v) << 16; return x.f;
}
__device__ __forceinline__ u16 f2bf(float f) {
  union { u32 u; float f; } x; x.f = f;
  return (u16)((x.u + 0x7fffu + ((x.u >> 16) & 1u)) >> 16);
}

__device__ __forceinline__ void gload16(const void* g, void* l) {
  __builtin_amdgcn_global_load_lds(
      (const __attribute__((address_space(1))) u32*)g,
      (__attribute__((address_space(3))) u32*)l, 16, 0, 0);
}

#define MFMA16(a, bfr, cacc) __builtin_amdgcn_mfma_f32_16x16x32_bf16((a), (bfr), (cacc), 0, 0, 0)

// ---------------- prep kernels ----------------

// fp32 -> bf16, 8 elements/thread
__global__ void convert_bf16_kernel(const float* __restrict__ in,
                                    u16* __restrict__ out, int n8) {
  int t = blockIdx.x * blockDim.x + threadIdx.x;
  if (t >= n8) return;
  const float4v* p = (const float4v*)(in + (size_t)t * 8);
  float4v a = p[0], b = p[1];
  union { bf16x8 v; u16 s[8]; } o;
  o.s[0] = f2bf(a[0]); o.s[1] = f2bf(a[1]); o.s[2] = f2bf(a[2]); o.s[3] = f2bf(a[3]);
  o.s[4] = f2bf(b[0]); o.s[5] = f2bf(b[1]); o.s[6] = f2bf(b[2]); o.s[7] = f2bf(b[3]);
  *(bf16x8*)(out + (size_t)t * 8) = o.v;
}

// out[c*R + r] = bf16(in[r*C + c])
__global__ void transpose_kernel(const float* __restrict__ in, u16* __restrict__ out,
                                 int R, int C) {
  int t = blockIdx.x * blockDim.x + threadIdx.x;
  if (t >= R * C) return;
  int c = t / R, r = t % R;
  out[t] = f2bf(in[r * C + c]);
}

__global__ void bias_tab_kernel(const float* __restrict__ w1, const float* __restrict__ w2,
                                float* __restrict__ tab) {
  int t = blockIdx.x * blockDim.x + threadIdx.x;
  if (t >= 225 * 16) return;
  int r = t >> 4, h = t & 15;
  int i = r / 15, j = r % 15;
  float gi = (float)(i - 7) * (8.0f / 7.0f);
  float gj = (float)(j - 7) * (8.0f / 7.0f);
  float si = (gi > 0.f) ? 1.f : ((gi < 0.f) ? -1.f : 0.f);
  float sj = (gj > 0.f) ? 1.f : ((gj < 0.f) ? -1.f : 0.f);
  float t0 = si * log2f(fabsf(gi) + 1.0f) * (1.0f / 3.0f);
  float t1 = sj * log2f(fabsf(gj) + 1.0f) * (1.0f / 3.0f);
  float acc = 0.f;
  for (int k = 0; k < 512; ++k) {
    float a = t0 * w1[k] + t1 * w1[512 + k];
    float hs = a * fminf(fmaxf(a + 3.f, 0.f), 6.f) * (1.f / 6.f);
    acc += hs * w2[k * 16 + h];
  }
  tab[t] = acc;
}

__global__ void bias16_kernel(const float* __restrict__ tab, float* __restrict__ b16) {
  int t = blockIdx.x * blockDim.x + threadIdx.x;
  if (t >= 16 * 64 * 64) return;
  int h = t >> 12, nm = t & 4095, n = nm >> 6, m = nm & 63;
  int idx = ((n >> 3) - (m >> 3) + 7) * 15 + ((n & 7) - (m & 7) + 7);
  float b = tab[idx * 16 + h];
  b16[t] = 16.0f / (1.0f + expf(-b));
}

// ---------------- m97-style bf16 GEMM (generic): C[M,N] = A * Bt^T ----------------
template <bool F32OUT>
__global__ __launch_bounds__(256) void gemm_bt(const u16* __restrict__ A,
                                               const u16* __restrict__ Bt,
                                               void* __restrict__ Cout,
                                               int M, int N, int K) {
  __shared__ u16 lA[128 * 64];
  __shared__ u16 lB[128 * 64];
  const int tid = threadIdx.x;
  const int w = tid >> 6, l = tid & 63;
  const int lg = l >> 4, li = l & 15;
  const int nbn = N >> 7;
  const int nwg = gridDim.x;
  int bidx = blockIdx.x;
  int q = nwg >> 3, r = nwg & 7;
  int xcd = bidx & 7, pos = bidx >> 3;
  int swz = (xcd < r ? xcd * (q + 1) : r * (q + 1) + (xcd - r) * q) + pos;
  int bm = swz / nbn, bn = swz % nbn;
  const int wr = w >> 1, wc = w & 1;

  f32x4 acc[4][4];
#pragma unroll
  for (int i = 0; i < 4; i++)
#pragma unroll
    for (int j = 0; j < 4; j++) acc[i][j] = (f32x4){0.f, 0.f, 0.f, 0.f};

  const u16* Abase = A + (size_t)(bm * 128) * K;
  const u16* Bbase = Bt + (size_t)(bn * 128) * K;

  for (int k0 = 0; k0 < K; k0 += 64) {
#pragma unroll
    for (int i = 0; i < 4; ++i) {
      int c = w * 256 + i * 64 + l;
      int row = c >> 3, kc = c & 7;
      gload16(Abase + (size_t)row * K + k0 + kc * 8, (u16*)lA + c * 8);
      gload16(Bbase + (size_t)row * K + k0 + kc * 8, (u16*)lB + c * 8);
    }
    __syncthreads();
#pragma unroll
    for (int kk = 0; kk < 2; ++kk) {
      bf16x8 af[4], bfr[4];
#pragma unroll
      for (int t = 0; t < 4; ++t) {
        int row = wr * 64 + t * 16 + li;
        af[t] = *(const bf16x8*)&lA[row * 64 + kk * 32 + lg * 8];
        int col = wc * 64 + t * 16 + li;
        bfr[t] = *(const bf16x8*)&lB[col * 64 + kk * 32 + lg * 8];
      }
#pragma unroll
      for (int tm = 0; tm < 4; ++tm)
#pragma unroll
        for (int tn = 0; tn < 4; ++tn)
          acc[tm][tn] = MFMA16(af[tm], bfr[tn], acc[tm][tn]);
    }
    __syncthreads();
  }
  int r0 = bm * 128 + wr * 64 + lg * 4;
  int c0 = bn * 128 + wc * 64 + li;
#pragma unroll
  for (int tm = 0; tm < 4; ++tm)
#pragma unroll
    for (int tn = 0; tn < 4; ++tn)
#pragma unroll
      for (int j = 0; j < 4; ++j) {
        size_t off = (size_t)(r0 + tm * 16 + j) * N + c0 + tn * 16;
        if (F32OUT)
          ((float*)Cout)[off] = acc[tm][tn][j];
        else
          ((u16*)Cout)[off] = f2bf(acc[tm][tn][j]);
      }
}

// ---------------- qkv GEMM with fused cosine-norm + head-major store --------------
// N=1536 fixed roles: bn 0-3 q (normalize*scale), 4-7 k (normalize), 8-11 v.
// Output layout: qkv_ws[((s*16+h)*2048 + b)*2048 + n*32 + d]  (bf16)
__global__ __launch_bounds__(256) void gemm_qkv(const u16* __restrict__ A,
                                                const u16* __restrict__ Bt,
                                                u16* __restrict__ Cq,
                                                const float* __restrict__ lscale,
                                                int M, int K) {
  __shared__ u16 lds[128 * 136];  // 34,816 B; lA/lB alias front, ct uses all
  u16* lA = lds;
  u16* lB = lds + 8192;
  const int tid = threadIdx.x;
  const int w = tid >> 6, l = tid & 63;
  const int lg = l >> 4, li = l & 15;
  const int nbn = 12;
  const int nwg = gridDim.x;
  int bidx = blockIdx.x;
  int q = nwg >> 3, r = nwg & 7;
  int xcd = bidx & 7, pos = bidx >> 3;
  int swz = (xcd < r ? xcd * (q + 1) : r * (q + 1) + (xcd - r) * q) + pos;
  int bm = swz / nbn, bn = swz % nbn;
  const int wr = w >> 1, wc = w & 1;

  f32x4 acc[4][4];
#pragma unroll
  for (int i = 0; i < 4; i++)
#pragma unroll
    for (int j = 0; j < 4; j++) acc[i][j] = (f32x4){0.f, 0.f, 0.f, 0.f};

  const u16* Abase = A + (size_t)(bm * 128) * K;
  const u16* Bbase = Bt + (size_t)(bn * 128) * K;

  for (int k0 = 0; k0 < K; k0 += 64) {
#pragma unroll
    for (int i = 0; i < 4; ++i) {
      int c = w * 256 + i * 64 + l;
      int row = c >> 3, kc = c & 7;
      gload16(Abase + (size_t)row * K + k0 + kc * 8, lA + c * 8);
      gload16(Bbase + (size_t)row * K + k0 + kc * 8, lB + c * 8);
    }
    __syncthreads();
#pragma unroll
    for (int kk = 0; kk < 2; ++kk) {
      bf16x8 af[4], bfr[4];
#pragma unroll
      for (int t = 0; t < 4; ++t) {
        int row = wr * 64 + t * 16 + li;
        af[t] = *(const bf16x8*)&lA[row * 64 + kk * 32 + lg * 8];
        int col = wc * 64 + t * 16 + li;
        bfr[t] = *(const bf16x8*)&lB[col * 64 + kk * 32 + lg * 8];
      }
#pragma unroll
      for (int tm = 0; tm < 4; ++tm)
#pragma unroll
        for (int tn = 0; tn < 4; ++tn)
          acc[tm][tn] = MFMA16(af[tm], bfr[tn], acc[tm][tn]);
    }
    __syncthreads();
  }

  // ---- fused epilogue: normalize q,k rows per head (d=32); fold scale into q ----
  const int s_t = bn >> 2;          // 0=q 1=k 2=v
  const int hq = (bn & 3) * 4;      // first head of this col-tile
  float scv[2];
  if (s_t == 0) {
    scv[0] = __expf(fminf(lscale[hq + wc * 2 + 0], 4.6051702f));
    scv[1] = __expf(fminf(lscale[hq + wc * 2 + 1], 4.6051702f));
  } else {
    scv[0] = scv[1] = 1.0f;
  }
  if (s_t < 2) {
#pragma unroll
    for (int tm = 0; tm < 4; ++tm)
#pragma unroll
      for (int g = 0; g < 2; ++g) {
        f32x4 s2;
#pragma unroll
        for (int j = 0; j < 4; ++j)
          s2[j] = acc[tm][2 * g][j] * acc[tm][2 * g][j] +
                  acc[tm][2 * g + 1][j] * acc[tm][2 * g + 1][j];
#pragma unroll
        for (int m = 1; m <= 8; m <<= 1)
#pragma unroll
          for (int j = 0; j < 4; ++j) s2[j] += __shfl_xor(s2[j], m);
#pragma unroll
        for (int j = 0; j < 4; ++j) {
          float rn = scv[g] / fmaxf(sqrtf(s2[j]), 1e-12f);
          acc[tm][2 * g][j] *= rn;
          acc[tm][2 * g + 1][j] *= rn;
        }
      }
  }
  // ---- bounce C tile to LDS (ct[128][136] u16), then head-major coalesced store --
  u16* ct = lds;
#pragma unroll
  for (int tm = 0; tm < 4; ++tm)
#pragma unroll
    for (int tn = 0; tn < 4; ++tn)
#pragma unroll
      for (int j = 0; j < 4; ++j)
        ct[(wr * 64 + tm * 16 + lg * 4 + j) * 136 + wc * 64 + tn * 16 + li] =
            f2bf(acc[tm][tn][j]);
  __syncthreads();
  {
    int rr = tid >> 2;           // 0..63 row within window
    int c8 = (tid & 3) * 8;      // col-in-head offset (0,8,16,24)
#pragma unroll
    for (int bh = 0; bh < 2; ++bh)
#pragma unroll
      for (int ht = 0; ht < 4; ++ht) {
        bf16x8 v = *(const bf16x8*)(ct + (bh * 64 + rr) * 136 + ht * 32 + c8);
        size_t base = ((size_t)(s_t * 16 + hq + ht) * 2048 + (bm * 2 + bh)) * 2048;
        *(bf16x8*)(Cq + base + rr * 32 + c8) = v;
      }
  }
}

// ---------------- attention-only: pre-normalized q,k,v in head-major layout -------
// 1 block = 1 window, 512 threads = 8 waves, wave w owns heads (w, w+8).
// LDS 66,560 B -> 2 blocks/CU. 16-key S chunks; softmax over heads; PV; bounced out.
__global__ __launch_bounds__(512, 2) void attn2(const u16* __restrict__ qkv,
                                                const float* __restrict__ mask,
                                                const float* __restrict__ bias16,
                                                u16* __restrict__ aout) {
  __shared__ float S[16 * 16 * 65];  // [h][m][65n] = 66,560 B
  u16* P16 = (u16*)S;
  float* ob = S;                     // epilogue alias [16][516]
  const int tid = threadIdx.x;
  const int w = tid >> 6, l = tid & 63;
  const int lg = l >> 4, li = l & 15;
  const int b = blockIdx.x, wm = b & 63;
  const float* mask_w = mask + wm * 4096;

  f32x4 oacc[2][4][2];
#pragma unroll
  for (int hp = 0; hp < 2; ++hp)
#pragma unroll
    for (int i = 0; i < 4; ++i) {
      oacc[hp][i][0] = (f32x4){0.f, 0.f, 0.f, 0.f};
      oacc[hp][i][1] = (f32x4){0.f, 0.f, 0.f, 0.f};
    }

#pragma unroll
  for (int c = 0; c < 4; ++c) {
    // ---- QK^T chunk (16 keys) + bias + mask -> S ----
#pragma unroll
    for (int hp = 0; hp < 2; ++hp) {
      int h = w + hp * 8;
      const u16* qb = qkv + ((size_t)h * 2048 + b) * 2048;
      const u16* kb = qkv + ((size_t)(16 + h) * 2048 + b) * 2048;
      const float* bias_h = bias16 + h * 4096;
      bf16x8 kfc = *(const bf16x8*)(kb + (c * 16 + li) * 32 + lg * 8);
      int mg = c * 16 + li;
#pragma unroll
      for (int tn = 0; tn < 4; ++tn) {
        bf16x8 qt = *(const bf16x8*)(qb + (tn * 16 + li) * 32 + lg * 8);
        f32x4 z = {0.f, 0.f, 0.f, 0.f};
        f32x4 s = MFMA16(qt, kfc, z);
#pragma unroll
        for (int j = 0; j < 4; ++j) {
          int n = tn * 16 + lg * 4 + j;
          S[h * 1040 + li * 65 + n] = s[j] + bias_h[n * 64 + mg] + mask_w[n * 64 + mg];
        }
      }
    }
    __syncthreads();
    // ---- softmax over 16 heads per (m,n): 1024 points / 512 threads ----
#pragma unroll
    for (int pp = 0; pp < 2; ++pp) {
      int p = tid + pp * 512;
      int base = (p >> 6) * 65 + (p & 63);
      float mx = -3.0e38f;
#pragma unroll
      for (int hh = 0; hh < 16; ++hh) mx = fmaxf(mx, S[hh * 1040 + base]);
      float sum = 0.f;
#pragma unroll
      for (int hh = 0; hh < 16; ++hh) {
        float e = __expf(S[hh * 1040 + base] - mx);
        S[hh * 1040 + base] = e;
        sum += e;
      }
      float inv = 1.0f / sum;
#pragma unroll
      for (int hh = 0; hh < 16; ++hh)
        P16[(hh * 1040 + base) * 2] = f2bf(S[hh * 1040 + base] * inv);
    }
    __syncthreads();
    // ---- PV (K=32 MFMA, upper 16 keys zero-padded) ----
#pragma unroll
    for (int hp = 0; hp < 2; ++hp) {
      int h = w + hp * 8;
      const u16* vb = qkv + ((size_t)(32 + h) * 2048 + b) * 2048;
      bf16x8 vf[2];
#pragma unroll
      for (int td = 0; td < 2; ++td)
#pragma unroll
        for (int e = 0; e < 8; ++e)
          vf[td][e] = (lg < 2)
                          ? (short)vb[(c * 16 + lg * 8 + e) * 32 + td * 16 + li]
                          : (short)0;
#pragma unroll
      for (int tn = 0; tn < 4; ++tn) {
        bf16x8 pf;
#pragma unroll
        for (int e = 0; e < 8; ++e)
          pf[e] = (lg < 2)
                      ? (short)P16[(h * 1040 + (lg * 8 + e) * 65 + tn * 16 + li) * 2]
                      : (short)0;
        oacc[hp][tn][0] = MFMA16(pf, vf[0], oacc[hp][tn][0]);
        oacc[hp][tn][1] = MFMA16(pf, vf[1], oacc[hp][tn][1]);
      }
    }
    __syncthreads();
  }

  // ---- epilogue: 4 row-passes through ob, coalesced stores ----
#pragma unroll
  for (int tn = 0; tn < 4; ++tn) {
#pragma unroll
    for (int hp = 0; hp < 2; ++hp) {
      int h = w + hp * 8;
#pragma unroll
      for (int td = 0; td < 2; ++td)
#pragma unroll
        for (int j = 0; j < 4; ++j)
          ob[(lg * 4 + j) * 516 + h * 32 + td * 16 + li] = oacc[hp][tn][td][j];
    }
    __syncthreads();
    {
      int rr = tid >> 5, c16 = (tid & 31) * 16;
      const float* src = ob + rr * 516 + c16;
      u16* dst = aout + ((size_t)b * 64 + tn * 16 + rr) * 512 + c16;
#pragma unroll
      for (int half = 0; half < 2; ++half) {
        union { bf16x8 v; u16 u[8]; } o;
#pragma unroll
        for (int e = 0; e < 8; ++e) o.u[e] = f2bf(src[half * 8 + e]);
        *(bf16x8*)(dst + half * 8) = o.v;
      }
    }
    __syncthreads();
  }
}

extern "C" void kernel_launch(void* const* d_in, const int* in_sizes, int n_in,
                              void* d_out, int out_size, void* d_ws, size_t ws_size,
                              hipStream_t stream) {
  const float* x = (const float*)d_in[0];
  const float* mask = (const float*)d_in[1];
  const float* w_qkv = (const float*)d_in[2];
  const float* w_out = (const float*)d_in[3];
  const float* cpb_w1 = (const float*)d_in[4];
  const float* cpb_w2 = (const float*)d_in[5];
  const float* lscale = (const float*)d_in[6];
  float* out = (float*)d_out;

  char* ws = (char*)d_ws;
  u16* wqkvT = (u16*)ws;                         // 1,572,864 B
  u16* woutT = (u16*)(ws + 1572864ull);          // 524,288 B
  float* btab = (float*)(ws + 2097152ull);       // 16,384 B
  float* b16 = (float*)(ws + 2113536ull);        // 262,144 B
  u16* qkv_ws = (u16*)(ws + 2375680ull);         // 402,653,184 B (head-major)
  u16* xb = (u16*)(ws + 2375680ull + 402653184ull);  // 134,217,728 B
  u16* attn_out = xb;  // alias: xb dead after gemm_qkv; attn2 runs after it

  // prep
  transpose_kernel<<<(512 * 1536 + 255) / 256, 256, 0, stream>>>(w_qkv, wqkvT, 512, 1536);
  transpose_kernel<<<(512 * 512 + 255) / 256, 256, 0, stream>>>(w_out, woutT, 512, 512);
  bias_tab_kernel<<<(225 * 16 + 255) / 256, 256, 0, stream>>>(cpb_w1, cpb_w2, btab);
  bias16_kernel<<<(16 * 64 * 64 + 255) / 256, 256, 0, stream>>>(btab, b16);

  // x -> bf16
  convert_bf16_kernel<<<(131072 * 64 + 255) / 256, 256, 0, stream>>>(x, xb, 131072 * 64);

  // qkv = xb @ w_qkv with fused norm/scale, head-major output
  gemm_qkv<<<12288, 256, 0, stream>>>(xb, wqkvT, qkv_ws, lscale, 131072, 512);

  // attention (reads qkv_ws, writes attn_out == xb)
  attn2<<<2048, 512, 0, stream>>>(qkv_ws, mask, b16, attn_out);

  // out = attn_out @ w_out (fp32 stores)
  gemm_bt<true><<<4096, 256, 0, stream>>>(attn_out, woutT, out, 131072, 512, 512);
}

// Round 10
// 944.724 us; speedup vs baseline: 1.0965x; 1.0490x over previous
//
#include <hip/hip_runtime.h>
#include <hip/hip_bf16.h>

typedef unsigned short u16;
typedef unsigned int u32;
typedef __attribute__((ext_vector_type(8))) short bf16x8;
typedef __attribute__((ext_vector_type(4))) float f32x4;
typedef __attribute__((ext_vector_type(4))) float float4v;

__device__ __forceinline__ float bf2f(u16 v) {
  union { u32 u; float f; } x; x.u = ((u32)v) << 16; return x.f;
}
__device__ __forceinline__ u16 f2bf(float f) {
  union { u32 u; float f; } x; x.f = f;
  return (u16)((x.u + 0x7fffu + ((x.u >> 16) & 1u)) >> 16);
}

__device__ __forceinline__ void gload16(const void* g, void* l) {
  __builtin_amdgcn_global_load_lds(
      (const __attribute__((address_space(1))) u32*)g,
      (__attribute__((address_space(3))) u32*)l, 16, 0, 0);
}

#define MFMA16(a, bfr, cacc) __builtin_amdgcn_mfma_f32_16x16x32_bf16((a), (bfr), (cacc), 0, 0, 0)

// ---------------- prep kernels ----------------

// fp32 -> bf16, 8 elements/thread
__global__ void convert_bf16_kernel(const float* __restrict__ in,
                                    u16* __restrict__ out, int n8) {
  int t = blockIdx.x * blockDim.x + threadIdx.x;
  if (t >= n8) return;
  const float4v* p = (const float4v*)(in + (size_t)t * 8);
  float4v a = p[0], b = p[1];
  union { bf16x8 v; u16 s[8]; } o;
  o.s[0] = f2bf(a[0]); o.s[1] = f2bf(a[1]); o.s[2] = f2bf(a[2]); o.s[3] = f2bf(a[3]);
  o.s[4] = f2bf(b[0]); o.s[5] = f2bf(b[1]); o.s[6] = f2bf(b[2]); o.s[7] = f2bf(b[3]);
  *(bf16x8*)(out + (size_t)t * 8) = o.v;
}

// out[c*R + r] = bf16(in[r*C + c])
__global__ void transpose_kernel(const float* __restrict__ in, u16* __restrict__ out,
                                 int R, int C) {
  int t = blockIdx.x * blockDim.x + threadIdx.x;
  if (t >= R * C) return;
  int c = t / R, r = t % R;
  out[t] = f2bf(in[r * C + c]);
}

__global__ void bias_tab_kernel(const float* __restrict__ w1, const float* __restrict__ w2,
                                float* __restrict__ tab) {
  int t = blockIdx.x * blockDim.x + threadIdx.x;
  if (t >= 225 * 16) return;
  int r = t >> 4, h = t & 15;
  int i = r / 15, j = r % 15;
  float gi = (float)(i - 7) * (8.0f / 7.0f);
  float gj = (float)(j - 7) * (8.0f / 7.0f);
  float si = (gi > 0.f) ? 1.f : ((gi < 0.f) ? -1.f : 0.f);
  float sj = (gj > 0.f) ? 1.f : ((gj < 0.f) ? -1.f : 0.f);
  float t0 = si * log2f(fabsf(gi) + 1.0f) * (1.0f / 3.0f);
  float t1 = sj * log2f(fabsf(gj) + 1.0f) * (1.0f / 3.0f);
  float acc = 0.f;
  for (int k = 0; k < 512; ++k) {
    float a = t0 * w1[k] + t1 * w1[512 + k];
    float hs = a * fminf(fmaxf(a + 3.f, 0.f), 6.f) * (1.f / 6.f);
    acc += hs * w2[k * 16 + h];
  }
  tab[t] = acc;
}

__global__ void bias16_kernel(const float* __restrict__ tab, float* __restrict__ b16) {
  int t = blockIdx.x * blockDim.x + threadIdx.x;
  if (t >= 16 * 64 * 64) return;
  int h = t >> 12, nm = t & 4095, n = nm >> 6, m = nm & 63;
  int idx = ((n >> 3) - (m >> 3) + 7) * 15 + ((n & 7) - (m & 7) + 7);
  float b = tab[idx * 16 + h];
  b16[t] = 16.0f / (1.0f + expf(-b));
}

// ---------------- m97-style bf16 GEMM (generic): C[M,N] = A * Bt^T ----------------
// T2 swizzle per rule 21: linear LDS dest + inverse-swizzled global SOURCE
// (chunk kc ^= row&7) + matching XOR on the read side -> 2-way (free) banks.
template <bool F32OUT>
__global__ __launch_bounds__(256) void gemm_bt(const u16* __restrict__ A,
                                               const u16* __restrict__ Bt,
                                               void* __restrict__ Cout,
                                               int M, int N, int K) {
  __shared__ u16 lA[128 * 64];
  __shared__ u16 lB[128 * 64];
  const int tid = threadIdx.x;
  const int w = tid >> 6, l = tid & 63;
  const int lg = l >> 4, li = l & 15;
  const int nbn = N >> 7;
  const int nwg = gridDim.x;
  int bidx = blockIdx.x;
  int q = nwg >> 3, r = nwg & 7;
  int xcd = bidx & 7, pos = bidx >> 3;
  int swz = (xcd < r ? xcd * (q + 1) : r * (q + 1) + (xcd - r) * q) + pos;
  int bm = swz / nbn, bn = swz % nbn;
  const int wr = w >> 1, wc = w & 1;

  f32x4 acc[4][4];
#pragma unroll
  for (int i = 0; i < 4; i++)
#pragma unroll
    for (int j = 0; j < 4; j++) acc[i][j] = (f32x4){0.f, 0.f, 0.f, 0.f};

  const u16* Abase = A + (size_t)(bm * 128) * K;
  const u16* Bbase = Bt + (size_t)(bn * 128) * K;

  for (int k0 = 0; k0 < K; k0 += 64) {
#pragma unroll
    for (int i = 0; i < 4; ++i) {
      int c = w * 256 + i * 64 + l;
      int row = c >> 3, kc = c & 7;
      int kcs = kc ^ (row & 7);  // source pre-swizzle
      gload16(Abase + (size_t)row * K + k0 + kcs * 8, (u16*)lA + c * 8);
      gload16(Bbase + (size_t)row * K + k0 + kcs * 8, (u16*)lB + c * 8);
    }
    __syncthreads();
#pragma unroll
    for (int kk = 0; kk < 2; ++kk) {
      bf16x8 af[4], bfr[4];
#pragma unroll
      for (int t = 0; t < 4; ++t) {
        int row = wr * 64 + t * 16 + li;
        af[t] = *(const bf16x8*)&lA[row * 64 + (((kk * 4 + lg) ^ (row & 7)) << 3)];
        int col = wc * 64 + t * 16 + li;
        bfr[t] = *(const bf16x8*)&lB[col * 64 + (((kk * 4 + lg) ^ (col & 7)) << 3)];
      }
#pragma unroll
      for (int tm = 0; tm < 4; ++tm)
#pragma unroll
        for (int tn = 0; tn < 4; ++tn)
          acc[tm][tn] = MFMA16(af[tm], bfr[tn], acc[tm][tn]);
    }
    __syncthreads();
  }
  int r0 = bm * 128 + wr * 64 + lg * 4;
  int c0 = bn * 128 + wc * 64 + li;
#pragma unroll
  for (int tm = 0; tm < 4; ++tm)
#pragma unroll
    for (int tn = 0; tn < 4; ++tn)
#pragma unroll
      for (int j = 0; j < 4; ++j) {
        size_t off = (size_t)(r0 + tm * 16 + j) * N + c0 + tn * 16;
        if (F32OUT)
          ((float*)Cout)[off] = acc[tm][tn][j];
        else
          ((u16*)Cout)[off] = f2bf(acc[tm][tn][j]);
      }
}

// ---------------- qkv GEMM with fused cosine-norm + head-major store --------------
// N=1536 fixed roles: bn 0-3 q (normalize*scale), 4-7 k (normalize), 8-11 v.
// Output layout: qkv_ws[((s*16+h)*2048 + b)*2048 + n*32 + d]  (bf16)
__global__ __launch_bounds__(256) void gemm_qkv(const u16* __restrict__ A,
                                                const u16* __restrict__ Bt,
                                                u16* __restrict__ Cq,
                                                const float* __restrict__ lscale,
                                                int M, int K) {
  __shared__ u16 lds[128 * 136];  // 34,816 B; lA/lB alias front, ct uses all
  u16* lA = lds;
  u16* lB = lds + 8192;
  const int tid = threadIdx.x;
  const int w = tid >> 6, l = tid & 63;
  const int lg = l >> 4, li = l & 15;
  const int nbn = 12;
  const int nwg = gridDim.x;
  int bidx = blockIdx.x;
  int q = nwg >> 3, r = nwg & 7;
  int xcd = bidx & 7, pos = bidx >> 3;
  int swz = (xcd < r ? xcd * (q + 1) : r * (q + 1) + (xcd - r) * q) + pos;
  int bm = swz / nbn, bn = swz % nbn;
  const int wr = w >> 1, wc = w & 1;

  f32x4 acc[4][4];
#pragma unroll
  for (int i = 0; i < 4; i++)
#pragma unroll
    for (int j = 0; j < 4; j++) acc[i][j] = (f32x4){0.f, 0.f, 0.f, 0.f};

  const u16* Abase = A + (size_t)(bm * 128) * K;
  const u16* Bbase = Bt + (size_t)(bn * 128) * K;

  for (int k0 = 0; k0 < K; k0 += 64) {
#pragma unroll
    for (int i = 0; i < 4; ++i) {
      int c = w * 256 + i * 64 + l;
      int row = c >> 3, kc = c & 7;
      int kcs = kc ^ (row & 7);  // source pre-swizzle
      gload16(Abase + (size_t)row * K + k0 + kcs * 8, lA + c * 8);
      gload16(Bbase + (size_t)row * K + k0 + kcs * 8, lB + c * 8);
    }
    __syncthreads();
#pragma unroll
    for (int kk = 0; kk < 2; ++kk) {
      bf16x8 af[4], bfr[4];
#pragma unroll
      for (int t = 0; t < 4; ++t) {
        int row = wr * 64 + t * 16 + li;
        af[t] = *(const bf16x8*)&lA[row * 64 + (((kk * 4 + lg) ^ (row & 7)) << 3)];
        int col = wc * 64 + t * 16 + li;
        bfr[t] = *(const bf16x8*)&lB[col * 64 + (((kk * 4 + lg) ^ (col & 7)) << 3)];
      }
#pragma unroll
      for (int tm = 0; tm < 4; ++tm)
#pragma unroll
        for (int tn = 0; tn < 4; ++tn)
          acc[tm][tn] = MFMA16(af[tm], bfr[tn], acc[tm][tn]);
    }
    __syncthreads();
  }

  // ---- fused epilogue: normalize q,k rows per head (d=32); fold scale into q ----
  const int s_t = bn >> 2;          // 0=q 1=k 2=v
  const int hq = (bn & 3) * 4;      // first head of this col-tile
  float scv[2];
  if (s_t == 0) {
    scv[0] = __expf(fminf(lscale[hq + wc * 2 + 0], 4.6051702f));
    scv[1] = __expf(fminf(lscale[hq + wc * 2 + 1], 4.6051702f));
  } else {
    scv[0] = scv[1] = 1.0f;
  }
  if (s_t < 2) {
#pragma unroll
    for (int tm = 0; tm < 4; ++tm)
#pragma unroll
      for (int g = 0; g < 2; ++g) {
        f32x4 s2;
#pragma unroll
        for (int j = 0; j < 4; ++j)
          s2[j] = acc[tm][2 * g][j] * acc[tm][2 * g][j] +
                  acc[tm][2 * g + 1][j] * acc[tm][2 * g + 1][j];
#pragma unroll
        for (int m = 1; m <= 8; m <<= 1)
#pragma unroll
          for (int j = 0; j < 4; ++j) s2[j] += __shfl_xor(s2[j], m);
#pragma unroll
        for (int j = 0; j < 4; ++j) {
          float rn = scv[g] / fmaxf(sqrtf(s2[j]), 1e-12f);
          acc[tm][2 * g][j] *= rn;
          acc[tm][2 * g + 1][j] *= rn;
        }
      }
  }
  // ---- bounce C tile to LDS (ct[128][136] u16), then head-major coalesced store --
  u16* ct = lds;
#pragma unroll
  for (int tm = 0; tm < 4; ++tm)
#pragma unroll
    for (int tn = 0; tn < 4; ++tn)
#pragma unroll
      for (int j = 0; j < 4; ++j)
        ct[(wr * 64 + tm * 16 + lg * 4 + j) * 136 + wc * 64 + tn * 16 + li] =
            f2bf(acc[tm][tn][j]);
  __syncthreads();
  {
    int rr = tid >> 2;           // 0..63 row within window
    int c8 = (tid & 3) * 8;      // col-in-head offset (0,8,16,24)
#pragma unroll
    for (int bh = 0; bh < 2; ++bh)
#pragma unroll
      for (int ht = 0; ht < 4; ++ht) {
        bf16x8 v = *(const bf16x8*)(ct + (bh * 64 + rr) * 136 + ht * 32 + c8);
        size_t base = ((size_t)(s_t * 16 + hq + ht) * 2048 + (bm * 2 + bh)) * 2048;
        *(bf16x8*)(Cq + base + rr * 32 + c8) = v;
      }
  }
}

// ---------------- attention-only: pre-normalized q,k,v in head-major layout -------
// 1 block = 1 window, 512 threads = 8 waves, wave w owns heads (w, w+8).
// LDS 66,560 B -> 2 blocks/CU. 16-key S chunks; softmax over heads; PV; bounced out.
__global__ __launch_bounds__(512, 2) void attn2(const u16* __restrict__ qkv,
                                                const float* __restrict__ mask,
                                                const float* __restrict__ bias16,
                                                u16* __restrict__ aout) {
  __shared__ float S[16 * 16 * 65];  // [h][m][65n] = 66,560 B
  u16* P16 = (u16*)S;
  float* ob = S;                     // epilogue alias [16][516]
  const int tid = threadIdx.x;
  const int w = tid >> 6, l = tid & 63;
  const int lg = l >> 4, li = l & 15;
  const int b = blockIdx.x, wm = b & 63;
  const float* mask_w = mask + wm * 4096;

  f32x4 oacc[2][4][2];
#pragma unroll
  for (int hp = 0; hp < 2; ++hp)
#pragma unroll
    for (int i = 0; i < 4; ++i) {
      oacc[hp][i][0] = (f32x4){0.f, 0.f, 0.f, 0.f};
      oacc[hp][i][1] = (f32x4){0.f, 0.f, 0.f, 0.f};
    }

#pragma unroll
  for (int c = 0; c < 4; ++c) {
    // ---- QK^T chunk (16 keys) + bias + mask -> S ----
#pragma unroll
    for (int hp = 0; hp < 2; ++hp) {
      int h = w + hp * 8;
      const u16* qb = qkv + ((size_t)h * 2048 + b) * 2048;
      const u16* kb = qkv + ((size_t)(16 + h) * 2048 + b) * 2048;
      const float* bias_h = bias16 + h * 4096;
      bf16x8 kfc = *(const bf16x8*)(kb + (c * 16 + li) * 32 + lg * 8);
      int mg = c * 16 + li;
#pragma unroll
      for (int tn = 0; tn < 4; ++tn) {
        bf16x8 qt = *(const bf16x8*)(qb + (tn * 16 + li) * 32 + lg * 8);
        f32x4 z = {0.f, 0.f, 0.f, 0.f};
        f32x4 s = MFMA16(qt, kfc, z);
#pragma unroll
        for (int j = 0; j < 4; ++j) {
          int n = tn * 16 + lg * 4 + j;
          S[h * 1040 + li * 65 + n] = s[j] + bias_h[n * 64 + mg] + mask_w[n * 64 + mg];
        }
      }
    }
    __syncthreads();
    // ---- softmax over 16 heads per (m,n): 1024 points / 512 threads ----
#pragma unroll
    for (int pp = 0; pp < 2; ++pp) {
      int p = tid + pp * 512;
      int base = (p >> 6) * 65 + (p & 63);
      float mx = -3.0e38f;
#pragma unroll
      for (int hh = 0; hh < 16; ++hh) mx = fmaxf(mx, S[hh * 1040 + base]);
      float sum = 0.f;
#pragma unroll
      for (int hh = 0; hh < 16; ++hh) {
        float e = __expf(S[hh * 1040 + base] - mx);
        S[hh * 1040 + base] = e;
        sum += e;
      }
      float inv = 1.0f / sum;
#pragma unroll
      for (int hh = 0; hh < 16; ++hh)
        P16[(hh * 1040 + base) * 2] = f2bf(S[hh * 1040 + base] * inv);
    }
    __syncthreads();
    // ---- PV (K=32 MFMA, upper 16 keys zero-padded) ----
#pragma unroll
    for (int hp = 0; hp < 2; ++hp) {
      int h = w + hp * 8;
      const u16* vb = qkv + ((size_t)(32 + h) * 2048 + b) * 2048;
      bf16x8 vf[2];
#pragma unroll
      for (int td = 0; td < 2; ++td)
#pragma unroll
        for (int e = 0; e < 8; ++e)
          vf[td][e] = (lg < 2)
                          ? (short)vb[(c * 16 + lg * 8 + e) * 32 + td * 16 + li]
                          : (short)0;
#pragma unroll
      for (int tn = 0; tn < 4; ++tn) {
        bf16x8 pf;
#pragma unroll
        for (int e = 0; e < 8; ++e)
          pf[e] = (lg < 2)
                      ? (short)P16[(h * 1040 + (lg * 8 + e) * 65 + tn * 16 + li) * 2]
                      : (short)0;
        oacc[hp][tn][0] = MFMA16(pf, vf[0], oacc[hp][tn][0]);
        oacc[hp][tn][1] = MFMA16(pf, vf[1], oacc[hp][tn][1]);
      }
    }
    __syncthreads();
  }

  // ---- epilogue: 4 row-passes through ob, coalesced stores ----
#pragma unroll
  for (int tn = 0; tn < 4; ++tn) {
#pragma unroll
    for (int hp = 0; hp < 2; ++hp) {
      int h = w + hp * 8;
#pragma unroll
      for (int td = 0; td < 2; ++td)
#pragma unroll
        for (int j = 0; j < 4; ++j)
          ob[(lg * 4 + j) * 516 + h * 32 + td * 16 + li] = oacc[hp][tn][td][j];
    }
    __syncthreads();
    {
      int rr = tid >> 5, c16 = (tid & 31) * 16;
      const float* src = ob + rr * 516 + c16;
      u16* dst = aout + ((size_t)b * 64 + tn * 16 + rr) * 512 + c16;
#pragma unroll
      for (int half = 0; half < 2; ++half) {
        union { bf16x8 v; u16 u[8]; } o;
#pragma unroll
        for (int e = 0; e < 8; ++e) o.u[e] = f2bf(src[half * 8 + e]);
        *(bf16x8*)(dst + half * 8) = o.v;
      }
    }
    __syncthreads();
  }
}

extern "C" void kernel_launch(void* const* d_in, const int* in_sizes, int n_in,
                              void* d_out, int out_size, void* d_ws, size_t ws_size,
                              hipStream_t stream) {
  const float* x = (const float*)d_in[0];
  const float* mask = (const float*)d_in[1];
  const float* w_qkv = (const float*)d_in[2];
  const float* w_out = (const float*)d_in[3];
  const float* cpb_w1 = (const float*)d_in[4];
  const float* cpb_w2 = (const float*)d_in[5];
  const float* lscale = (const float*)d_in[6];
  float* out = (float*)d_out;

  char* ws = (char*)d_ws;
  u16* wqkvT = (u16*)ws;                         // 1,572,864 B
  u16* woutT = (u16*)(ws + 1572864ull);          // 524,288 B
  float* btab = (float*)(ws + 2097152ull);       // 16,384 B
  float* b16 = (float*)(ws + 2113536ull);        // 262,144 B
  u16* qkv_ws = (u16*)(ws + 2375680ull);         // 402,653,184 B (head-major)
  u16* xb = (u16*)(ws + 2375680ull + 402653184ull);  // 134,217,728 B
  u16* attn_out = xb;  // alias: xb dead after gemm_qkv; attn2 runs after it

  // prep
  transpose_kernel<<<(512 * 1536 + 255) / 256, 256, 0, stream>>>(w_qkv, wqkvT, 512, 1536);
  transpose_kernel<<<(512 * 512 + 255) / 256, 256, 0, stream>>>(w_out, woutT, 512, 512);
  bias_tab_kernel<<<(225 * 16 + 255) / 256, 256, 0, stream>>>(cpb_w1, cpb_w2, btab);
  bias16_kernel<<<(16 * 64 * 64 + 255) / 256, 256, 0, stream>>>(btab, b16);

  // x -> bf16
  convert_bf16_kernel<<<(131072 * 64 + 255) / 256, 256, 0, stream>>>(x, xb, 131072 * 64);

  // qkv = xb @ w_qkv with fused norm/scale, head-major output
  gemm_qkv<<<12288, 256, 0, stream>>>(xb, wqkvT, qkv_ws, lscale, 131072, 512);

  // attention (reads qkv_ws, writes attn_out == xb)
  attn2<<<2048, 512, 0, stream>>>(qkv_ws, mask, b16, attn_out);

  // out = attn_out @ w_out (fp32 stores)
  gemm_bt<true><<<4096, 256, 0, stream>>>(attn_out, woutT, out, 131072, 512, 512);
}